// Round 5
// baseline (187.326 us; speedup 1.0000x reference)
//
#include <hip/hip_runtime.h>
#include <hip/hip_bf16.h>
#include <math.h>

#define B_ 2
#define S_ 2048
#define D_ 1024
#define H_ 16
#define HKV_ 4
#define DH_ 64
#define NTOK (B_*S_)     // 4096
#define NQK 1280         // q(1024) + k(256) fused cols
#define NQKV 1536        // + v

typedef __attribute__((ext_vector_type(8))) short short8;
typedef __attribute__((ext_vector_type(4))) float floatx4;

__device__ __forceinline__ short f2bf(float f) {
    union { __hip_bfloat16 h; short s; } u;
    u.h = __float2bfloat16(f);
    return u.s;
}
__device__ __forceinline__ float bf2f(short s) {
    union { __hip_bfloat16 h; short t; } u;
    u.t = s;
    return __bfloat162float(u.h);
}
__device__ __forceinline__ unsigned pack2(float a, float b) {
    return (unsigned)(unsigned short)f2bf(a) | ((unsigned)(unsigned short)f2bf(b) << 16);
}

__device__ __forceinline__ void gload_lds16(const void* g, void* l) {
    __builtin_amdgcn_global_load_lds(
        (const __attribute__((address_space(1))) void*)g,
        (__attribute__((address_space(3))) void*)l, 16, 0, 0);
}

// ---------------- fused prep: x->bf16 convert + 4 weight transposes --------
__global__ __launch_bounds__(256) void prep_kernel(
    const float* __restrict__ x,  const float* __restrict__ Wq,
    const float* __restrict__ Wk, const float* __restrict__ Wv,
    const float* __restrict__ Wo,
    short* __restrict__ xb, short* __restrict__ wt, short* __restrict__ woT)
{
    int bid = blockIdx.x;
    if (bid < 4096) {
        int i = bid * 256 + threadIdx.x;
        float4 v = ((const float4*)x)[i];
        short4 o = { f2bf(v.x), f2bf(v.y), f2bf(v.z), f2bf(v.w) };
        ((short4*)xb)[i] = o;
        return;
    }
    bid -= 4096;
    const float* src; short* dst; int N;
    if (bid < 1024)      { src = Wq; dst = wt;                        N = 1024; }
    else if (bid < 1280) { bid -= 1024; src = Wk; dst = wt + (size_t)1024 * 1024; N = 256; }
    else if (bid < 1536) { bid -= 1280; src = Wv; dst = wt + (size_t)1280 * 1024; N = 256; }
    else                 { bid -= 1536; src = Wo; dst = woT;          N = 1024; }
    __shared__ float t[32][33];
    int tiles_n = N / 32;
    int n0 = (bid % tiles_n) * 32, k0 = (bid / tiles_n) * 32;
    int tx = threadIdx.x & 31, ty = threadIdx.x >> 5;
    #pragma unroll
    for (int i = 0; i < 4; ++i)
        t[ty + 8 * i][tx] = src[(size_t)(k0 + ty + 8 * i) * N + n0 + tx];
    __syncthreads();
    #pragma unroll
    for (int i = 0; i < 4; ++i)
        dst[(size_t)(n0 + ty + 8 * i) * 1024 + k0 + tx] = f2bf(t[tx][ty + 8 * i]);
}

// ---------------- GEMM: C[M,N] = A[M,1024] @ Bt[N,1024]^T (bf16 MFMA) -------
// m97 shape: 128x128 tile, BK=32, 256 thr = 4 waves (2x2), wave 64x64 = 4x4.
// Double-buffered LDS + single raw s_barrier per K-step, manual vmcnt(0) on
// loads issued one full iteration earlier (prefetch stays in flight across
// the barrier; no compiler full-drain).
template<int MODE>
__global__ __launch_bounds__(256) void gemm_tn_kernel(
    const short* __restrict__ A, const short* __restrict__ Bt,
    short* __restrict__ Cb, float* __restrict__ Cf, short* __restrict__ Ct,
    int ldc)
{
    __shared__ short As[2][128 * 32];
    __shared__ short Bs[2][128 * 32];
    const int K = 1024;
    const int tid = threadIdx.x;
    const int bm0 = blockIdx.y * 128;
    const int bn0 = blockIdx.x * 128;
    const int lane = tid & 63, w = tid >> 6;
    const int wm = w >> 1, wn = w & 1;
    const int lm = lane & 15, quad = lane >> 4;

    floatx4 acc[4][4] = {};

    const int r0  = tid >> 2;
    const int kb0 = (tid & 3) * 16;

    auto stage = [&](int kt, int buf) {
        const char* gaA = (const char*)A  + ((size_t)(bm0 + r0) * K + kt) * 2 + kb0;
        const char* gaB = (const char*)Bt + ((size_t)(bn0 + r0) * K + kt) * 2 + kb0;
        gload_lds16(gaA,                      (char*)As[buf] + tid * 16);
        gload_lds16(gaA + (size_t)64 * K * 2, (char*)As[buf] + 4096 + tid * 16);
        gload_lds16(gaB,                      (char*)Bs[buf] + tid * 16);
        gload_lds16(gaB + (size_t)64 * K * 2, (char*)Bs[buf] + 4096 + tid * 16);
    };

    stage(0, 0);
    for (int kt = 0; kt < K; kt += 32) {
        const int buf = (kt >> 5) & 1;
        asm volatile("s_waitcnt vmcnt(0)" ::: "memory");
        asm volatile("s_barrier" ::: "memory");
        if (kt + 32 < K) stage(kt + 32, buf ^ 1);

        short8 af[4], bf[4];
        #pragma unroll
        for (int mt = 0; mt < 4; ++mt)
            af[mt] = *(const short8*)&As[buf][(wm * 64 + mt * 16 + lm) * 32 + quad * 8];
        #pragma unroll
        for (int nt = 0; nt < 4; ++nt)
            bf[nt] = *(const short8*)&Bs[buf][(wn * 64 + nt * 16 + lm) * 32 + quad * 8];
        #pragma unroll
        for (int mt = 0; mt < 4; ++mt)
            #pragma unroll
            for (int nt = 0; nt < 4; ++nt)
                acc[mt][nt] = __builtin_amdgcn_mfma_f32_16x16x32_bf16(
                    af[mt], bf[nt], acc[mt][nt], 0, 0, 0);
    }

    const int row_base = bm0 + wm * 64;
    const int col_base = bn0 + wn * 64;
    if (MODE == 2 && bn0 >= NQK) {  // V tiles -> transposed store
        #pragma unroll
        for (int mt = 0; mt < 4; ++mt)
            #pragma unroll
            for (int nt = 0; nt < 4; ++nt) {
                int vcol = col_base + nt * 16 + lm - NQK;
                int row0 = row_base + mt * 16 + quad * 4;
                short4 o = { f2bf(acc[mt][nt][0]), f2bf(acc[mt][nt][1]),
                             f2bf(acc[mt][nt][2]), f2bf(acc[mt][nt][3]) };
                *(short4*)&Ct[(size_t)vcol * NTOK + row0] = o;
            }
    } else if (MODE == 1) {
        #pragma unroll
        for (int mt = 0; mt < 4; ++mt)
            #pragma unroll
            for (int nt = 0; nt < 4; ++nt)
                #pragma unroll
                for (int r = 0; r < 4; ++r) {
                    int row = row_base + mt * 16 + quad * 4 + r;
                    int col = col_base + nt * 16 + lm;
                    Cf[(size_t)row * ldc + col] = acc[mt][nt][r];
                }
    } else {
        #pragma unroll
        for (int mt = 0; mt < 4; ++mt)
            #pragma unroll
            for (int nt = 0; nt < 4; ++nt)
                #pragma unroll
                for (int r = 0; r < 4; ++r) {
                    int row = row_base + mt * 16 + quad * 4 + r;
                    int col = col_base + nt * 16 + lm;
                    Cb[(size_t)row * ldc + col] = f2bf(acc[mt][nt][r]);
                }
    }
}

// ---------------- RoPE in-place on qkb [NTOK][1280], 20 heads of 64 --------
__global__ __launch_bounds__(256) void rope_kernel(short* __restrict__ x,
                                                   const int* __restrict__ poff)
{
    int idx = blockIdx.x * 256 + threadIdx.x;
    if (idx >= NTOK * 20 * 32) return;
    int p   = idx & 31;
    int hd  = (idx >> 5) % 20;
    int tok = idx / (32 * 20);
    int s   = tok & (S_ - 1);
    float t = (float)(s + poff[0]);
    float invf = exp2f(-0.415241012f * (float)p);   // 10000^(-p/32)
    float ang = t * invf;
    float sn, c;
    sincosf(ang, &sn, &c);
    size_t base = (size_t)tok * NQK + hd * 64 + p;
    float x1 = bf2f(x[base]), x2 = bf2f(x[base + 32]);
    x[base]      = f2bf(x1 * c - x2 * sn);
    x[base + 32] = f2bf(x2 * c + x1 * sn);
}

// ---------------- Flash attention v5 ----------------
// Block = (bh, c-swizzled), 4 waves = strips 4c..4c+3. Single raw s_barrier
// per tile (manual vmcnt on prefetched loads). Diagonal tile peeled (mask-free
// main loop). l accumulated via MFMA with all-ones A (lacc[0] = l[q] in-lane).
__global__ __launch_bounds__(256, 4) void attn_kernel5(
    const short* __restrict__ qk,  // [NTOK][1280]
    const short* __restrict__ vT,  // [256][NTOK]
    short* __restrict__ attn)      // [NTOK][1024]
{
    __shared__ short Ks[2][64 * 64];
    __shared__ short Vs[2][64 * 64];
    __shared__ short Ps[4][16 * 64];   // per-wave P^T / transpose scratch

    const int tid = threadIdx.x;
    const int lane = tid & 63, w = tid >> 6;
    const int lm = lane & 15, quad = lane >> 4;

    const int bid = blockIdx.x;
    const int bh = bid & 31;
    const int cid = bid >> 5;
    const int c = cid ^ ((cid & 8) ? 7 : 0);   // balance c across CU siblings
    const int h = bh & 15, b = bh >> 4, g = h >> 2;
    const int r0 = (c * 4 + w) * 16;           // this wave's q-strip base row

    const short* qbase = qk + (size_t)b * S_ * NQK;
    const short* kptr  = qbase + 1024 + g * 64;
    const short* vptr  = vT + (size_t)g * 64 * NTOK + (size_t)b * S_;
    short* Pw = Ps[w];

    short8 Q0 = *(const short8*)(qbase + (size_t)(r0 + lm) * NQK + h * 64 + quad * 8);
    short8 Q1 = *(const short8*)(qbase + (size_t)(r0 + lm) * NQK + h * 64 + 32 + quad * 8);

    short8 ones8;
    #pragma unroll
    for (int i = 0; i < 8; ++i) ones8[i] = (short)0x3F80;  // bf16 1.0

    floatx4 O[4] = {};
    floatx4 lacc = {};
    const float qs = 0.125f * 1.44269504f;   // 1/sqrt(64) * log2(e)

    const int sr = tid >> 3;   // 0..31
    const int cc = tid & 7;

    auto stage = [&](int kt2, int buf2) {
        const int k0s = kt2 * 64;
        #pragma unroll
        for (int i = 0; i < 2; ++i) {
            int r  = i * 32 + sr;
            int gc = cc ^ (r & 7);   // LDS chunk slot cc holds global chunk gc
            gload_lds16(kptr + (size_t)(k0s + r) * NQK + gc * 8,
                        (char*)(&Ks[buf2][0]) + (i * 256 + tid) * 16);
            gload_lds16(vptr + (size_t)r * NTOK + k0s + gc * 8,
                        (char*)(&Vs[buf2][0]) + (i * 256 + tid) * 16);
        }
    };

    auto tile = [&](int kt, bool diag) {
        const int buf = kt & 1;
        const int k0 = kt * 64;
        // ---- S^T = K @ Q^T ----
        floatx4 sc[4];
        #pragma unroll
        for (int nt = 0; nt < 4; ++nt) {
            int key = nt * 16 + lm, sw = key & 7;
            short8 kf0 = *(const short8*)&Ks[buf][key * 64 + ((quad ^ sw) * 8)];
            short8 kf1 = *(const short8*)&Ks[buf][key * 64 + (((quad + 4) ^ sw) * 8)];
            floatx4 s = {};
            s = __builtin_amdgcn_mfma_f32_16x16x32_bf16(kf0, Q0, s, 0, 0, 0);
            s = __builtin_amdgcn_mfma_f32_16x16x32_bf16(kf1, Q1, s, 0, 0, 0);
            sc[nt] = s;
        }
        // ---- fixed-max exp2 + P^T b64-pair writes (swizzled) ----
        #pragma unroll
        for (int nt = 0; nt < 4; ++nt) {
            float e[4];
            #pragma unroll
            for (int r = 0; r < 4; ++r) {
                float v = exp2f(fmaf(sc[nt][r], qs, -24.f));
                if (diag && (k0 + nt * 16 + quad * 4 + r) > (r0 + lm)) v = 0.f;
                e[r] = v;
            }
            int chunk = (2 * nt + (quad >> 1)) ^ (lm & 7);
            uint2 pv = { pack2(e[0], e[1]), pack2(e[2], e[3]) };
            *(uint2*)&Pw[lm * 64 + chunk * 8 + (quad & 1) * 4] = pv;
        }
        asm volatile("s_waitcnt lgkmcnt(0)" ::: "memory");
        short8 bp0 = *(const short8*)&Pw[lm * 64 + ((quad ^ (lm & 7)) * 8)];
        short8 bp1 = *(const short8*)&Pw[lm * 64 + (((quad + 4) ^ (lm & 7)) * 8)];
        // ---- O^T += V^T @ P^T ; l += 1 @ P^T ----
        #pragma unroll
        for (int nt = 0; nt < 4; ++nt) {
            int d = nt * 16 + lm, sw = d & 7;
            short8 vf0 = *(const short8*)&Vs[buf][d * 64 + ((quad ^ sw) * 8)];
            short8 vf1 = *(const short8*)&Vs[buf][d * 64 + (((quad + 4) ^ sw) * 8)];
            O[nt] = __builtin_amdgcn_mfma_f32_16x16x32_bf16(vf0, bp0, O[nt], 0, 0, 0);
            O[nt] = __builtin_amdgcn_mfma_f32_16x16x32_bf16(vf1, bp1, O[nt], 0, 0, 0);
        }
        lacc = __builtin_amdgcn_mfma_f32_16x16x32_bf16(ones8, bp0, lacc, 0, 0, 0);
        lacc = __builtin_amdgcn_mfma_f32_16x16x32_bf16(ones8, bp1, lacc, 0, 0, 0);
    };

    stage(0, 0);
    for (int kt = 0; kt < c; ++kt) {
        asm volatile("s_waitcnt vmcnt(0)" ::: "memory");
        asm volatile("s_barrier" ::: "memory");
        stage(kt + 1, (kt + 1) & 1);
        tile(kt, false);
    }
    asm volatile("s_waitcnt vmcnt(0)" ::: "memory");
    asm volatile("s_barrier" ::: "memory");
    tile(c, true);

    // ---- finalize: normalize by lacc[0] (= l[q=lm]), transpose via Pw ----
    float linv = 1.0f / lacc[0];
    #pragma unroll
    for (int nt = 0; nt < 4; ++nt) {
        int chunk = (2 * nt + (quad >> 1)) ^ (lm & 7);
        uint2 pv = { pack2(O[nt][0] * linv, O[nt][1] * linv),
                     pack2(O[nt][2] * linv, O[nt][3] * linv) };
        *(uint2*)&Pw[lm * 64 + chunk * 8 + (quad & 1) * 4] = pv;
    }
    asm volatile("s_waitcnt lgkmcnt(0)" ::: "memory");
    short* ob = attn + (size_t)b * S_ * D_ + h * 64;
    #pragma unroll
    for (int nt = 0; nt < 4; ++nt)
        #pragma unroll
        for (int rr = 0; rr < 4; ++rr) {
            int q7 = (quad * 4 + rr) & 7;
            int chunk = (2 * nt + (lm >> 3)) ^ q7;
            short vv = Pw[(quad * 4 + rr) * 64 + chunk * 8 + (lm & 7)];
            ob[(size_t)(r0 + quad * 4 + rr) * D_ + nt * 16 + lm] = vv;
        }
}

extern "C" void kernel_launch(void* const* d_in, const int* in_sizes, int n_in,
                              void* d_out, int out_size, void* d_ws, size_t ws_size,
                              hipStream_t stream) {
    const float* x  = (const float*)d_in[0];
    const float* Wq = (const float*)d_in[1];
    const float* Wk = (const float*)d_in[2];
    const float* Wv = (const float*)d_in[3];
    const float* Wo = (const float*)d_in[4];
    const int* poff = (const int*)d_in[5];
    float* out = (float*)d_out;

    short* xb  = (short*)d_ws;                      // [4096][1024]
    short* wt  = xb  + (size_t)NTOK * D_;           // [1536][1024] fused Wqkv^T
    short* woT = wt  + (size_t)NQKV * D_;           // [1024][1024] Wo^T
    short* qkb = woT + (size_t)D_ * D_;             // [4096][1280]
    short* vbT = qkb + (size_t)NTOK * NQK;          // [256][4096]
    short* ab  = vbT + (size_t)(HKV_*DH_) * NTOK;   // [4096][1024]

    prep_kernel<<<dim3(4096 + 1024 + 256 + 256 + 1024), 256, 0, stream>>>(
        x, Wq, Wk, Wv, Wo, xb, wt, woT);
    // fused QKV projection (V tiles stored transposed to vbT)
    gemm_tn_kernel<2><<<dim3(NQKV / 128, NTOK / 128), 256, 0, stream>>>(
        xb, wt, qkb, nullptr, vbT, NQK);
    rope_kernel<<<dim3(NTOK * 20 * 32 / 256), 256, 0, stream>>>(qkb, poff);
    attn_kernel5<<<dim3(1024), 256, 0, stream>>>(qkb, vbT, ab);
    // output projection
    gemm_tn_kernel<1><<<dim3(D_ / 128, NTOK / 128), 256, 0, stream>>>(
        ab, woT, nullptr, out, nullptr, D_);
}

// Round 6
// 185.285 us; speedup vs baseline: 1.0110x; 1.0110x over previous
//
#include <hip/hip_runtime.h>
#include <hip/hip_bf16.h>
#include <math.h>

#define B_ 2
#define S_ 2048
#define D_ 1024
#define H_ 16
#define HKV_ 4
#define DH_ 64
#define NTOK (B_*S_)     // 4096
#define NQK 1280         // q(1024) + k(256) fused cols
#define NQKV 1536        // + v

typedef __attribute__((ext_vector_type(8))) short short8;
typedef __attribute__((ext_vector_type(4))) float floatx4;

__device__ __forceinline__ short f2bf(float f) {
    union { __hip_bfloat16 h; short s; } u;
    u.h = __float2bfloat16(f);
    return u.s;
}
__device__ __forceinline__ float bf2f(short s) {
    union { __hip_bfloat16 h; short t; } u;
    u.t = s;
    return __bfloat162float(u.h);
}
__device__ __forceinline__ unsigned pack2(float a, float b) {
    return (unsigned)(unsigned short)f2bf(a) | ((unsigned)(unsigned short)f2bf(b) << 16);
}

__device__ __forceinline__ void gload_lds16(const void* g, void* l) {
    __builtin_amdgcn_global_load_lds(
        (const __attribute__((address_space(1))) void*)g,
        (__attribute__((address_space(3))) void*)l, 16, 0, 0);
}

// ---------------- fused prep: x->bf16 convert + 4 weight transposes --------
__global__ __launch_bounds__(256) void prep_kernel(
    const float* __restrict__ x,  const float* __restrict__ Wq,
    const float* __restrict__ Wk, const float* __restrict__ Wv,
    const float* __restrict__ Wo,
    short* __restrict__ xb, short* __restrict__ wt, short* __restrict__ woT)
{
    int bid = blockIdx.x;
    if (bid < 4096) {
        int i = bid * 256 + threadIdx.x;
        float4 v = ((const float4*)x)[i];
        short4 o = { f2bf(v.x), f2bf(v.y), f2bf(v.z), f2bf(v.w) };
        ((short4*)xb)[i] = o;
        return;
    }
    bid -= 4096;
    const float* src; short* dst; int N;
    if (bid < 1024)      { src = Wq; dst = wt;                        N = 1024; }
    else if (bid < 1280) { bid -= 1024; src = Wk; dst = wt + (size_t)1024 * 1024; N = 256; }
    else if (bid < 1536) { bid -= 1280; src = Wv; dst = wt + (size_t)1280 * 1024; N = 256; }
    else                 { bid -= 1536; src = Wo; dst = woT;          N = 1024; }
    __shared__ float t[32][33];
    int tiles_n = N / 32;
    int n0 = (bid % tiles_n) * 32, k0 = (bid / tiles_n) * 32;
    int tx = threadIdx.x & 31, ty = threadIdx.x >> 5;
    #pragma unroll
    for (int i = 0; i < 4; ++i)
        t[ty + 8 * i][tx] = src[(size_t)(k0 + ty + 8 * i) * N + n0 + tx];
    __syncthreads();
    #pragma unroll
    for (int i = 0; i < 4; ++i)
        dst[(size_t)(n0 + ty + 8 * i) * 1024 + k0 + tx] = f2bf(t[tx][ty + 8 * i]);
}

// ---------------- GEMM: C[M,N] = A[M,1024] @ Bt[N,1024]^T (bf16 MFMA) -------
// 64x128 tile (more blocks -> grid no longer starves CUs), BK=32, 256 thr =
// 4 waves side-by-side in N; wave computes 64x32 (acc 4x2). Double-buffered
// LDS + single raw s_barrier per K-step.
template<int MODE>
__global__ __launch_bounds__(256, 4) void gemm_tn_kernel(
    const short* __restrict__ A, const short* __restrict__ Bt,
    short* __restrict__ Cb, float* __restrict__ Cf, short* __restrict__ Ct,
    int ldc)
{
    __shared__ short As[2][64 * 32];
    __shared__ short Bs[2][128 * 32];
    const int K = 1024;
    const int tid = threadIdx.x;
    const int bm0 = blockIdx.y * 64;
    const int bn0 = blockIdx.x * 128;
    const int lane = tid & 63, wn = tid >> 6;
    const int lm = lane & 15, quad = lane >> 4;

    floatx4 acc[4][2] = {};

    const int r0  = tid >> 2;         // 0..63
    const int kb0 = (tid & 3) * 16;

    auto stage = [&](int kt, int buf) {
        const char* gaA = (const char*)A  + ((size_t)(bm0 + r0) * K + kt) * 2 + kb0;
        const char* gaB = (const char*)Bt + ((size_t)(bn0 + r0) * K + kt) * 2 + kb0;
        gload_lds16(gaA,                      (char*)As[buf] + tid * 16);
        gload_lds16(gaB,                      (char*)Bs[buf] + tid * 16);
        gload_lds16(gaB + (size_t)64 * K * 2, (char*)Bs[buf] + 4096 + tid * 16);
    };

    stage(0, 0);
    for (int kt = 0; kt < K; kt += 32) {
        const int buf = (kt >> 5) & 1;
        asm volatile("s_waitcnt vmcnt(0)" ::: "memory");
        asm volatile("s_barrier" ::: "memory");
        if (kt + 32 < K) stage(kt + 32, buf ^ 1);

        short8 af[4], bfr[2];
        #pragma unroll
        for (int mt = 0; mt < 4; ++mt)
            af[mt] = *(const short8*)&As[buf][(mt * 16 + lm) * 32 + quad * 8];
        #pragma unroll
        for (int nt = 0; nt < 2; ++nt)
            bfr[nt] = *(const short8*)&Bs[buf][(wn * 32 + nt * 16 + lm) * 32 + quad * 8];
        #pragma unroll
        for (int mt = 0; mt < 4; ++mt)
            #pragma unroll
            for (int nt = 0; nt < 2; ++nt)
                acc[mt][nt] = __builtin_amdgcn_mfma_f32_16x16x32_bf16(
                    af[mt], bfr[nt], acc[mt][nt], 0, 0, 0);
    }

    const int col_base = bn0 + wn * 32;
    if (MODE == 2 && bn0 >= NQK) {  // V tiles -> transposed store
        #pragma unroll
        for (int mt = 0; mt < 4; ++mt)
            #pragma unroll
            for (int nt = 0; nt < 2; ++nt) {
                int vcol = col_base + nt * 16 + lm - NQK;
                int row0 = bm0 + mt * 16 + quad * 4;
                short4 o = { f2bf(acc[mt][nt][0]), f2bf(acc[mt][nt][1]),
                             f2bf(acc[mt][nt][2]), f2bf(acc[mt][nt][3]) };
                *(short4*)&Ct[(size_t)vcol * NTOK + row0] = o;
            }
    } else if (MODE == 1) {
        #pragma unroll
        for (int mt = 0; mt < 4; ++mt)
            #pragma unroll
            for (int nt = 0; nt < 2; ++nt)
                #pragma unroll
                for (int r = 0; r < 4; ++r) {
                    int row = bm0 + mt * 16 + quad * 4 + r;
                    int col = col_base + nt * 16 + lm;
                    Cf[(size_t)row * ldc + col] = acc[mt][nt][r];
                }
    } else {
        #pragma unroll
        for (int mt = 0; mt < 4; ++mt)
            #pragma unroll
            for (int nt = 0; nt < 2; ++nt)
                #pragma unroll
                for (int r = 0; r < 4; ++r) {
                    int row = bm0 + mt * 16 + quad * 4 + r;
                    int col = col_base + nt * 16 + lm;
                    Cb[(size_t)row * ldc + col] = f2bf(acc[mt][nt][r]);
                }
    }
}

// ---------------- RoPE in-place on qkb [NTOK][1280], 20 heads of 64 --------
__global__ __launch_bounds__(256) void rope_kernel(short* __restrict__ x,
                                                   const int* __restrict__ poff)
{
    int idx = blockIdx.x * 256 + threadIdx.x;
    if (idx >= NTOK * 20 * 32) return;
    int p   = idx & 31;
    int hd  = (idx >> 5) % 20;
    int tok = idx / (32 * 20);
    int s   = tok & (S_ - 1);
    float t = (float)(s + poff[0]);
    float invf = exp2f(-0.415241012f * (float)p);   // 10000^(-p/32)
    float ang = t * invf;
    float sn, c;
    sincosf(ang, &sn, &c);
    size_t base = (size_t)tok * NQK + hd * 64 + p;
    float x1 = bf2f(x[base]), x2 = bf2f(x[base + 32]);
    x[base]      = f2bf(x1 * c - x2 * sn);
    x[base + 32] = f2bf(x2 * c + x1 * sn);
}

// ---------------- Flash attention v6: split-k jobs + refill ----------------
// Fixed-max softmax => partial (O,l) are additive. Jobs:
//   jid <  1024: (bh, c=31-(idx>>1), half) for c>=16 -> fp32 partials
//   jid >= 1024: (bh, c=15-(j>>5))            c<16  -> direct bf16 out
// Big jobs first => LPT scheduling via HW refill (1536 blocks, 4/CU resident).
__global__ __launch_bounds__(256, 4) void attn_kernel6(
    const short* __restrict__ qk,  // [NTOK][1280]
    const short* __restrict__ vT,  // [256][NTOK]
    short* __restrict__ attn,      // [NTOK][1024]
    float* __restrict__ Opart,     // [1024][64][64]
    float* __restrict__ lpart)     // [1024][64]
{
    __shared__ short Ks[2][64 * 64];
    __shared__ short Vs[2][64 * 64];
    __shared__ short Ps[4][16 * 64];

    const int tid = threadIdx.x;
    const int lane = tid & 63, w = tid >> 6;
    const int lm = lane & 15, quad = lane >> 4;

    const int jid = blockIdx.x;
    int bh, c, kt0, kt1, pslot;
    if (jid < 1024) {
        bh = jid & 31;
        int idx = jid >> 5;
        int cm = 15 - (idx >> 1);        // 15..0 -> c = 31..16 (big first)
        c = 16 + cm;
        int half = idx & 1;
        int h1 = (c + 2) >> 1;
        kt0 = half ? h1 : 0;
        kt1 = half ? (c + 1) : h1;
        pslot = (bh * 16 + cm) * 2 + half;
    } else {
        int j = jid - 1024;
        bh = j & 31;
        c = 15 - (j >> 5);               // 15..0 (big first)
        kt0 = 0; kt1 = c + 1; pslot = -1;
    }
    const int h = bh & 15, b = bh >> 4, g = h >> 2;
    const int r0 = (c * 4 + w) * 16;

    const short* qbase = qk + (size_t)b * S_ * NQK;
    const short* kptr  = qbase + 1024 + g * 64;
    const short* vptr  = vT + (size_t)g * 64 * NTOK + (size_t)b * S_;
    short* Pw = Ps[w];

    short8 Q0 = *(const short8*)(qbase + (size_t)(r0 + lm) * NQK + h * 64 + quad * 8);
    short8 Q1 = *(const short8*)(qbase + (size_t)(r0 + lm) * NQK + h * 64 + 32 + quad * 8);

    short8 ones8;
    #pragma unroll
    for (int i = 0; i < 8; ++i) ones8[i] = (short)0x3F80;  // bf16 1.0

    floatx4 O[4] = {};
    floatx4 lacc = {};
    const float qs = 0.125f * 1.44269504f;

    const int sr = tid >> 3;
    const int cc = tid & 7;

    auto stage = [&](int kt2, int buf2) {
        const int k0s = kt2 * 64;
        #pragma unroll
        for (int i = 0; i < 2; ++i) {
            int r  = i * 32 + sr;
            int gc = cc ^ (r & 7);
            gload_lds16(kptr + (size_t)(k0s + r) * NQK + gc * 8,
                        (char*)(&Ks[buf2][0]) + (i * 256 + tid) * 16);
            gload_lds16(vptr + (size_t)r * NTOK + k0s + gc * 8,
                        (char*)(&Vs[buf2][0]) + (i * 256 + tid) * 16);
        }
    };

    auto tile = [&](int kt, int buf, bool diag) {
        const int k0 = kt * 64;
        floatx4 sc[4];
        #pragma unroll
        for (int nt = 0; nt < 4; ++nt) {
            int key = nt * 16 + lm, sw = key & 7;
            short8 kf0 = *(const short8*)&Ks[buf][key * 64 + ((quad ^ sw) * 8)];
            short8 kf1 = *(const short8*)&Ks[buf][key * 64 + (((quad + 4) ^ sw) * 8)];
            floatx4 s = {};
            s = __builtin_amdgcn_mfma_f32_16x16x32_bf16(kf0, Q0, s, 0, 0, 0);
            s = __builtin_amdgcn_mfma_f32_16x16x32_bf16(kf1, Q1, s, 0, 0, 0);
            sc[nt] = s;
        }
        #pragma unroll
        for (int nt = 0; nt < 4; ++nt) {
            float e[4];
            #pragma unroll
            for (int r = 0; r < 4; ++r) {
                float v = exp2f(fmaf(sc[nt][r], qs, -24.f));
                if (diag && (k0 + nt * 16 + quad * 4 + r) > (r0 + lm)) v = 0.f;
                e[r] = v;
            }
            int chunk = (2 * nt + (quad >> 1)) ^ (lm & 7);
            uint2 pv = { pack2(e[0], e[1]), pack2(e[2], e[3]) };
            *(uint2*)&Pw[lm * 64 + chunk * 8 + (quad & 1) * 4] = pv;
        }
        asm volatile("s_waitcnt lgkmcnt(0)" ::: "memory");
        short8 bp0 = *(const short8*)&Pw[lm * 64 + ((quad ^ (lm & 7)) * 8)];
        short8 bp1 = *(const short8*)&Pw[lm * 64 + (((quad + 4) ^ (lm & 7)) * 8)];
        #pragma unroll
        for (int nt = 0; nt < 4; ++nt) {
            int d = nt * 16 + lm, sw = d & 7;
            short8 vf0 = *(const short8*)&Vs[buf][d * 64 + ((quad ^ sw) * 8)];
            short8 vf1 = *(const short8*)&Vs[buf][d * 64 + (((quad + 4) ^ sw) * 8)];
            O[nt] = __builtin_amdgcn_mfma_f32_16x16x32_bf16(vf0, bp0, O[nt], 0, 0, 0);
            O[nt] = __builtin_amdgcn_mfma_f32_16x16x32_bf16(vf1, bp1, O[nt], 0, 0, 0);
        }
        lacc = __builtin_amdgcn_mfma_f32_16x16x32_bf16(ones8, bp0, lacc, 0, 0, 0);
        lacc = __builtin_amdgcn_mfma_f32_16x16x32_bf16(ones8, bp1, lacc, 0, 0, 0);
    };

    stage(kt0, 0);
    for (int kt = kt0; kt < kt1; ++kt) {
        const int buf = (kt - kt0) & 1;
        asm volatile("s_waitcnt vmcnt(0)" ::: "memory");
        asm volatile("s_barrier" ::: "memory");
        if (kt + 1 < kt1) stage(kt + 1, buf ^ 1);
        tile(kt, buf, kt == c);
    }

    if (pslot >= 0) {
        // fp32 partial store: Opart[pslot][d][q], lpart[pslot][q]
        float* op = Opart + (size_t)pslot * 4096;
        #pragma unroll
        for (int nt = 0; nt < 4; ++nt)
            #pragma unroll
            for (int r = 0; r < 4; ++r)
                op[(nt * 16 + quad * 4 + r) * 64 + w * 16 + lm] = O[nt][r];
        if (quad == 0) lpart[pslot * 64 + w * 16 + lm] = lacc[0];
        return;
    }
    // direct path: normalize by lacc[0] (= l[q=lm]), transpose via Pw
    float linv = 1.0f / lacc[0];
    #pragma unroll
    for (int nt = 0; nt < 4; ++nt) {
        int chunk = (2 * nt + (quad >> 1)) ^ (lm & 7);
        uint2 pv = { pack2(O[nt][0] * linv, O[nt][1] * linv),
                     pack2(O[nt][2] * linv, O[nt][3] * linv) };
        *(uint2*)&Pw[lm * 64 + chunk * 8 + (quad & 1) * 4] = pv;
    }
    asm volatile("s_waitcnt lgkmcnt(0)" ::: "memory");
    short* ob = attn + (size_t)b * S_ * D_ + h * 64;
    #pragma unroll
    for (int nt = 0; nt < 4; ++nt)
        #pragma unroll
        for (int rr = 0; rr < 4; ++rr) {
            int q7 = (quad * 4 + rr) & 7;
            int chunk = (2 * nt + (lm >> 3)) ^ q7;
            short vv = Pw[(quad * 4 + rr) * 64 + chunk * 8 + (lm & 7)];
            ob[(size_t)(r0 + quad * 4 + rr) * D_ + nt * 16 + lm] = vv;
        }
}

// ---------------- merge split-k partials: 512 blocks (bh, cm) --------------
__global__ __launch_bounds__(256) void attn_merge_kernel(
    const float* __restrict__ Opart, const float* __restrict__ lpart,
    short* __restrict__ attn)
{
    __shared__ float Ot[64 * 65];
    __shared__ float ls[64];
    const int bid = blockIdx.x;
    const int bh = bid & 31, cm = bid >> 5;
    const int h = bh & 15, b = bh >> 4;
    const int c = 16 + cm;
    const int p0 = (bh * 16 + cm) * 2;
    const int tid = threadIdx.x;

    if (tid < 64)
        ls[tid] = lpart[p0 * 64 + tid] + lpart[(p0 + 1) * 64 + tid];
    __syncthreads();

    const float* o0 = Opart + (size_t)p0 * 4096;
    const float* o1 = o0 + 4096;
    int d = tid >> 2, q0 = (tid & 3) * 16;
    #pragma unroll
    for (int j = 0; j < 4; ++j) {
        int off = d * 64 + q0 + j * 4;
        float4 a = *(const float4*)(o0 + off);
        float4 bv = *(const float4*)(o1 + off);
        Ot[d * 65 + q0 + j * 4 + 0] = (a.x + bv.x) / ls[q0 + j * 4 + 0];
        Ot[d * 65 + q0 + j * 4 + 1] = (a.y + bv.y) / ls[q0 + j * 4 + 1];
        Ot[d * 65 + q0 + j * 4 + 2] = (a.z + bv.z) / ls[q0 + j * 4 + 2];
        Ot[d * 65 + q0 + j * 4 + 3] = (a.w + bv.w) / ls[q0 + j * 4 + 3];
    }
    __syncthreads();
    int q = tid & 63, db = tid >> 6;
    alignas(16) short vals[16];
    #pragma unroll
    for (int j = 0; j < 16; ++j)
        vals[j] = f2bf(Ot[(db * 16 + j) * 65 + q]);
    short* ob = attn + (size_t)(b * S_ + c * 64 + q) * D_ + h * 64 + db * 16;
    *(uint4*)ob     = *(const uint4*)&vals[0];
    *(uint4*)(ob+8) = *(const uint4*)&vals[8];
}

extern "C" void kernel_launch(void* const* d_in, const int* in_sizes, int n_in,
                              void* d_out, int out_size, void* d_ws, size_t ws_size,
                              hipStream_t stream) {
    const float* x  = (const float*)d_in[0];
    const float* Wq = (const float*)d_in[1];
    const float* Wk = (const float*)d_in[2];
    const float* Wv = (const float*)d_in[3];
    const float* Wo = (const float*)d_in[4];
    const int* poff = (const int*)d_in[5];
    float* out = (float*)d_out;

    short* xb  = (short*)d_ws;                      // [4096][1024]
    short* wt  = xb  + (size_t)NTOK * D_;           // [1536][1024] fused Wqkv^T
    short* woT = wt  + (size_t)NQKV * D_;           // [1024][1024] Wo^T
    short* qkb = woT + (size_t)D_ * D_;             // [4096][1280]
    short* vbT = qkb + (size_t)NTOK * NQK;          // [256][4096]
    short* ab  = vbT + (size_t)(HKV_*DH_) * NTOK;   // [4096][1024]
    float* Opart = (float*)(ab + (size_t)NTOK * D_); // [1024][64][64] fp32
    float* lpart = Opart + (size_t)1024 * 4096;      // [1024][64] fp32

    prep_kernel<<<dim3(4096 + 1024 + 256 + 256 + 1024), 256, 0, stream>>>(
        x, Wq, Wk, Wv, Wo, xb, wt, woT);
    gemm_tn_kernel<2><<<dim3(NQKV / 128, NTOK / 64), 256, 0, stream>>>(
        xb, wt, qkb, nullptr, vbT, NQK);
    rope_kernel<<<dim3(NTOK * 20 * 32 / 256), 256, 0, stream>>>(qkb, poff);
    attn_kernel6<<<dim3(1536), 256, 0, stream>>>(qkb, vbT, ab, Opart, lpart);
    attn_merge_kernel<<<dim3(512), 256, 0, stream>>>(Opart, lpart, ab);
    gemm_tn_kernel<1><<<dim3(D_ / 128, NTOK / 64), 256, 0, stream>>>(
        ab, woT, nullptr, out, nullptr, D_);
}

// Round 7
// 182.637 us; speedup vs baseline: 1.0257x; 1.0145x over previous
//
#include <hip/hip_runtime.h>
#include <hip/hip_bf16.h>
#include <math.h>

#define B_ 2
#define S_ 2048
#define D_ 1024
#define H_ 16
#define HKV_ 4
#define DH_ 64
#define NTOK (B_*S_)     // 4096
#define NQK 1280         // q(1024) + k(256) fused cols
#define NQKV 1536        // + v

typedef __attribute__((ext_vector_type(8))) short short8;
typedef __attribute__((ext_vector_type(4))) float floatx4;

__device__ __forceinline__ short f2bf(float f) {
    union { __hip_bfloat16 h; short s; } u;
    u.h = __float2bfloat16(f);
    return u.s;
}
__device__ __forceinline__ float bf2f(short s) {
    union { __hip_bfloat16 h; short t; } u;
    u.t = s;
    return __bfloat162float(u.h);
}
__device__ __forceinline__ unsigned fbits(float f) {
    union { float f; unsigned u; } u; u.f = f; return u.u;
}
// pack hi16(a) | hi16(b)<<16 in ONE v_perm_b32 (RTZ bf16 truncation)
__device__ __forceinline__ unsigned packhi(float a, float b) {
    return __builtin_amdgcn_perm(fbits(b), fbits(a), 0x07060302u);
}
__device__ __forceinline__ unsigned pack2(float a, float b) {
    return (unsigned)(unsigned short)f2bf(a) | ((unsigned)(unsigned short)f2bf(b) << 16);
}

__device__ __forceinline__ void gload_lds16(const void* g, void* l) {
    __builtin_amdgcn_global_load_lds(
        (const __attribute__((address_space(1))) void*)g,
        (__attribute__((address_space(3))) void*)l, 16, 0, 0);
}

// ---------------- fused prep: x->bf16 convert + 4 weight transposes --------
__global__ __launch_bounds__(256) void prep_kernel(
    const float* __restrict__ x,  const float* __restrict__ Wq,
    const float* __restrict__ Wk, const float* __restrict__ Wv,
    const float* __restrict__ Wo,
    short* __restrict__ xb, short* __restrict__ wt, short* __restrict__ woT)
{
    int bid = blockIdx.x;
    if (bid < 4096) {
        int i = bid * 256 + threadIdx.x;
        float4 v = ((const float4*)x)[i];
        short4 o = { f2bf(v.x), f2bf(v.y), f2bf(v.z), f2bf(v.w) };
        ((short4*)xb)[i] = o;
        return;
    }
    bid -= 4096;
    const float* src; short* dst; int N;
    if (bid < 1024)      { src = Wq; dst = wt;                        N = 1024; }
    else if (bid < 1280) { bid -= 1024; src = Wk; dst = wt + (size_t)1024 * 1024; N = 256; }
    else if (bid < 1536) { bid -= 1280; src = Wv; dst = wt + (size_t)1280 * 1024; N = 256; }
    else                 { bid -= 1536; src = Wo; dst = woT;          N = 1024; }
    __shared__ float t[32][33];
    int tiles_n = N / 32;
    int n0 = (bid % tiles_n) * 32, k0 = (bid / tiles_n) * 32;
    int tx = threadIdx.x & 31, ty = threadIdx.x >> 5;
    #pragma unroll
    for (int i = 0; i < 4; ++i)
        t[ty + 8 * i][tx] = src[(size_t)(k0 + ty + 8 * i) * N + n0 + tx];
    __syncthreads();
    #pragma unroll
    for (int i = 0; i < 4; ++i)
        dst[(size_t)(n0 + ty + 8 * i) * 1024 + k0 + tx] = f2bf(t[tx][ty + 8 * i]);
}

// ---------------- GEMM: C[M,N] = A[M,1024] @ Bt[N,1024]^T (bf16 MFMA) -------
// 64x128 tile, BK=32, 256 thr = 4 waves in N; wave 64x32 (acc 4x2).
// 3-stage LDS pipeline: stage kt+2 each iter, wait vmcnt(3) (tile kt landed,
// kt+1/kt+2 still in flight across the barrier -> latency covered 2 iters).
template<int MODE>
__global__ __launch_bounds__(256, 4) void gemm_tn_kernel(
    const short* __restrict__ A, const short* __restrict__ Bt,
    short* __restrict__ Cb, float* __restrict__ Cf, short* __restrict__ Ct,
    int ldc)
{
    __shared__ short As[3][64 * 32];
    __shared__ short Bs[3][128 * 32];
    const int K = 1024;
    const int tid = threadIdx.x;
    const int bm0 = blockIdx.y * 64;
    const int bn0 = blockIdx.x * 128;
    const int lane = tid & 63, wn = tid >> 6;
    const int lm = lane & 15, quad = lane >> 4;

    floatx4 acc[4][2] = {};

    const int r0  = tid >> 2;         // 0..63
    const int kb0 = (tid & 3) * 16;

    auto stage = [&](int kt, int buf) {
        const char* gaA = (const char*)A  + ((size_t)(bm0 + r0) * K + kt) * 2 + kb0;
        const char* gaB = (const char*)Bt + ((size_t)(bn0 + r0) * K + kt) * 2 + kb0;
        gload_lds16(gaA,                      (char*)As[buf] + tid * 16);
        gload_lds16(gaB,                      (char*)Bs[buf] + tid * 16);
        gload_lds16(gaB + (size_t)64 * K * 2, (char*)Bs[buf] + 4096 + tid * 16);
    };

    stage(0, 0);
    stage(32, 1);
    for (int kt = 0; kt < K; kt += 32) {
        const int it = kt >> 5;
        const int buf = it % 3;
        if (it < (K / 32) - 1) asm volatile("s_waitcnt vmcnt(3)" ::: "memory");
        else                   asm volatile("s_waitcnt vmcnt(0)" ::: "memory");
        asm volatile("s_barrier" ::: "memory");
        if (kt + 64 < K) stage(kt + 64, (it + 2) % 3);

        short8 af[4], bfr[2];
        #pragma unroll
        for (int mt = 0; mt < 4; ++mt)
            af[mt] = *(const short8*)&As[buf][(mt * 16 + lm) * 32 + quad * 8];
        #pragma unroll
        for (int nt = 0; nt < 2; ++nt)
            bfr[nt] = *(const short8*)&Bs[buf][(wn * 32 + nt * 16 + lm) * 32 + quad * 8];
        #pragma unroll
        for (int mt = 0; mt < 4; ++mt)
            #pragma unroll
            for (int nt = 0; nt < 2; ++nt)
                acc[mt][nt] = __builtin_amdgcn_mfma_f32_16x16x32_bf16(
                    af[mt], bfr[nt], acc[mt][nt], 0, 0, 0);
    }

    const int col_base = bn0 + wn * 32;
    if (MODE == 2 && bn0 >= NQK) {  // V tiles -> transposed store
        #pragma unroll
        for (int mt = 0; mt < 4; ++mt)
            #pragma unroll
            for (int nt = 0; nt < 2; ++nt) {
                int vcol = col_base + nt * 16 + lm - NQK;
                int row0 = bm0 + mt * 16 + quad * 4;
                short4 o = { f2bf(acc[mt][nt][0]), f2bf(acc[mt][nt][1]),
                             f2bf(acc[mt][nt][2]), f2bf(acc[mt][nt][3]) };
                *(short4*)&Ct[(size_t)vcol * NTOK + row0] = o;
            }
    } else if (MODE == 1) {
        #pragma unroll
        for (int mt = 0; mt < 4; ++mt)
            #pragma unroll
            for (int nt = 0; nt < 2; ++nt)
                #pragma unroll
                for (int r = 0; r < 4; ++r) {
                    int row = bm0 + mt * 16 + quad * 4 + r;
                    int col = col_base + nt * 16 + lm;
                    Cf[(size_t)row * ldc + col] = acc[mt][nt][r];
                }
    } else {
        #pragma unroll
        for (int mt = 0; mt < 4; ++mt)
            #pragma unroll
            for (int nt = 0; nt < 2; ++nt)
                #pragma unroll
                for (int r = 0; r < 4; ++r) {
                    int row = bm0 + mt * 16 + quad * 4 + r;
                    int col = col_base + nt * 16 + lm;
                    Cb[(size_t)row * ldc + col] = f2bf(acc[mt][nt][r]);
                }
    }
}

// ---------------- RoPE in-place on K only: qkb cols [1024,1280) ------------
__global__ __launch_bounds__(256) void ropek_kernel(short* __restrict__ x,
                                                    const int* __restrict__ poff)
{
    int idx = blockIdx.x * 256 + threadIdx.x;
    if (idx >= NTOK * 4 * 32) return;
    int p   = idx & 31;
    int hd  = (idx >> 5) & 3;
    int tok = idx >> 7;
    int s   = tok & (S_ - 1);
    float t = (float)(s + poff[0]);
    float invf = exp2f(-0.415241012f * (float)p);   // 10000^(-p/32)
    float ang = t * invf;
    float sn, c;
    sincosf(ang, &sn, &c);
    size_t base = (size_t)tok * NQK + 1024 + hd * 64 + p;
    float x1 = bf2f(x[base]), x2 = bf2f(x[base + 32]);
    x[base]      = f2bf(x1 * c - x2 * sn);
    x[base + 32] = f2bf(x2 * c + x1 * sn);
}

// ---------------- Flash attention v7: split-k + VALU diet ------------------
// Q-RoPE + softmax scale folded into Q fragments at job setup (in-register).
// exp2 directly on scores (no bias, no fma). P packed via v_perm truncation.
__global__ __launch_bounds__(256, 4) void attn_kernel7(
    const short* __restrict__ qk,  // [NTOK][1280], q cols raw (rope here)
    const short* __restrict__ vT,  // [256][NTOK]
    short* __restrict__ attn,      // [NTOK][1024]
    float* __restrict__ Opart,     // [1024][64][64]
    float* __restrict__ lpart,     // [1024][64]
    const int* __restrict__ poff)
{
    __shared__ short Ks[2][64 * 64];
    __shared__ short Vs[2][64 * 64];
    __shared__ short Ps[4][16 * 64];

    const int tid = threadIdx.x;
    const int lane = tid & 63, w = tid >> 6;
    const int lm = lane & 15, quad = lane >> 4;

    const int jid = blockIdx.x;
    int bh, c, kt0, kt1, pslot;
    if (jid < 1024) {
        bh = jid & 31;
        int idx = jid >> 5;
        int cm = 15 - (idx >> 1);        // 15..0 -> c = 31..16 (big first)
        c = 16 + cm;
        int half = idx & 1;
        int h1 = (c + 2) >> 1;
        kt0 = half ? h1 : 0;
        kt1 = half ? (c + 1) : h1;
        pslot = (bh * 16 + cm) * 2 + half;
    } else {
        int j = jid - 1024;
        bh = j & 31;
        c = 15 - (j >> 5);               // 15..0 (big first)
        kt0 = 0; kt1 = c + 1; pslot = -1;
    }
    const int h = bh & 15, b = bh >> 4, g = h >> 2;
    const int r0 = (c * 4 + w) * 16;

    const short* qbase = qk + (size_t)b * S_ * NQK;
    const short* kptr  = qbase + 1024 + g * 64;
    const short* vptr  = vT + (size_t)g * 64 * NTOK + (size_t)b * S_;
    short* Pw = Ps[w];

    // ---- load Q and apply RoPE + qs scale in-register ----
    // Q0[j] holds d0=quad*8+j (<32), Q1[j] holds d0+32: rotation pair in-lane.
    short8 Q0, Q1;
    {
        short8 q0r = *(const short8*)(qbase + (size_t)(r0 + lm) * NQK + h * 64 + quad * 8);
        short8 q1r = *(const short8*)(qbase + (size_t)(r0 + lm) * NQK + h * 64 + 32 + quad * 8);
        const float qs = 0.125f * 1.44269504f;  // 1/sqrt(64)*log2(e)
        float t = (float)(r0 + lm + poff[0]);
        #pragma unroll
        for (int j = 0; j < 8; ++j) {
            int p = quad * 8 + j;
            float invf = exp2f(-0.415241012f * (float)p);
            float ang = t * invf;
            float sn, cs;
            sincosf(ang, &sn, &cs);
            float x1 = bf2f(q0r[j]), x2 = bf2f(q1r[j]);
            Q0[j] = f2bf(qs * (x1 * cs - x2 * sn));
            Q1[j] = f2bf(qs * (x2 * cs + x1 * sn));
        }
    }

    short8 ones8;
    #pragma unroll
    for (int i = 0; i < 8; ++i) ones8[i] = (short)0x3F80;  // bf16 1.0

    floatx4 O[4] = {};
    floatx4 lacc = {};

    const int sr = tid >> 3;
    const int cc = tid & 7;

    auto stage = [&](int kt2, int buf2) {
        const int k0s = kt2 * 64;
        #pragma unroll
        for (int i = 0; i < 2; ++i) {
            int r  = i * 32 + sr;
            int gc = cc ^ (r & 7);
            gload_lds16(kptr + (size_t)(k0s + r) * NQK + gc * 8,
                        (char*)(&Ks[buf2][0]) + (i * 256 + tid) * 16);
            gload_lds16(vptr + (size_t)r * NTOK + k0s + gc * 8,
                        (char*)(&Vs[buf2][0]) + (i * 256 + tid) * 16);
        }
    };

    auto tile = [&](int kt, int buf, bool diag) {
        const int k0 = kt * 64;
        floatx4 sc[4];
        #pragma unroll
        for (int nt = 0; nt < 4; ++nt) {
            int key = nt * 16 + lm, sw = key & 7;
            short8 kf0 = *(const short8*)&Ks[buf][key * 64 + ((quad ^ sw) * 8)];
            short8 kf1 = *(const short8*)&Ks[buf][key * 64 + (((quad + 4) ^ sw) * 8)];
            floatx4 s = {};
            s = __builtin_amdgcn_mfma_f32_16x16x32_bf16(kf0, Q0, s, 0, 0, 0);
            s = __builtin_amdgcn_mfma_f32_16x16x32_bf16(kf1, Q1, s, 0, 0, 0);
            sc[nt] = s;
        }
        #pragma unroll
        for (int nt = 0; nt < 4; ++nt) {
            float e[4];
            #pragma unroll
            for (int r = 0; r < 4; ++r) {
                float v = exp2f(sc[nt][r]);
                if (diag && (k0 + nt * 16 + quad * 4 + r) > (r0 + lm)) v = 0.f;
                e[r] = v;
            }
            int chunk = (2 * nt + (quad >> 1)) ^ (lm & 7);
            uint2 pv = { packhi(e[0], e[1]), packhi(e[2], e[3]) };
            *(uint2*)&Pw[lm * 64 + chunk * 8 + (quad & 1) * 4] = pv;
        }
        asm volatile("s_waitcnt lgkmcnt(0)" ::: "memory");
        short8 bp0 = *(const short8*)&Pw[lm * 64 + ((quad ^ (lm & 7)) * 8)];
        short8 bp1 = *(const short8*)&Pw[lm * 64 + (((quad + 4) ^ (lm & 7)) * 8)];
        #pragma unroll
        for (int nt = 0; nt < 4; ++nt) {
            int d = nt * 16 + lm, sw = d & 7;
            short8 vf0 = *(const short8*)&Vs[buf][d * 64 + ((quad ^ sw) * 8)];
            short8 vf1 = *(const short8*)&Vs[buf][d * 64 + (((quad + 4) ^ sw) * 8)];
            O[nt] = __builtin_amdgcn_mfma_f32_16x16x32_bf16(vf0, bp0, O[nt], 0, 0, 0);
            O[nt] = __builtin_amdgcn_mfma_f32_16x16x32_bf16(vf1, bp1, O[nt], 0, 0, 0);
        }
        lacc = __builtin_amdgcn_mfma_f32_16x16x32_bf16(ones8, bp0, lacc, 0, 0, 0);
        lacc = __builtin_amdgcn_mfma_f32_16x16x32_bf16(ones8, bp1, lacc, 0, 0, 0);
    };

    stage(kt0, 0);
    for (int kt = kt0; kt < kt1; ++kt) {
        const int buf = (kt - kt0) & 1;
        asm volatile("s_waitcnt vmcnt(0)" ::: "memory");
        asm volatile("s_barrier" ::: "memory");
        if (kt + 1 < kt1) stage(kt + 1, buf ^ 1);
        tile(kt, buf, kt == c);
    }

    if (pslot >= 0) {
        float* op = Opart + (size_t)pslot * 4096;
        #pragma unroll
        for (int nt = 0; nt < 4; ++nt)
            #pragma unroll
            for (int r = 0; r < 4; ++r)
                op[(nt * 16 + quad * 4 + r) * 64 + w * 16 + lm] = O[nt][r];
        if (quad == 0) lpart[pslot * 64 + w * 16 + lm] = lacc[0];
        return;
    }
    // direct path: normalize by lacc[0] (= l[q=lm]), transpose via Pw
    float linv = 1.0f / lacc[0];
    #pragma unroll
    for (int nt = 0; nt < 4; ++nt) {
        int chunk = (2 * nt + (quad >> 1)) ^ (lm & 7);
        uint2 pv = { pack2(O[nt][0] * linv, O[nt][1] * linv),
                     pack2(O[nt][2] * linv, O[nt][3] * linv) };
        *(uint2*)&Pw[lm * 64 + chunk * 8 + (quad & 1) * 4] = pv;
    }
    asm volatile("s_waitcnt lgkmcnt(0)" ::: "memory");
    short* ob = attn + (size_t)b * S_ * D_ + h * 64;
    #pragma unroll
    for (int nt = 0; nt < 4; ++nt)
        #pragma unroll
        for (int rr = 0; rr < 4; ++rr) {
            int q7 = (quad * 4 + rr) & 7;
            int chunk = (2 * nt + (lm >> 3)) ^ q7;
            short vv = Pw[(quad * 4 + rr) * 64 + chunk * 8 + (lm & 7)];
            ob[(size_t)(r0 + quad * 4 + rr) * D_ + nt * 16 + lm] = vv;
        }
}

// ---------------- merge split-k partials: 512 blocks (bh, cm) --------------
__global__ __launch_bounds__(256) void attn_merge_kernel(
    const float* __restrict__ Opart, const float* __restrict__ lpart,
    short* __restrict__ attn)
{
    __shared__ float Ot[64 * 65];
    __shared__ float ls[64];
    const int bid = blockIdx.x;
    const int bh = bid & 31, cm = bid >> 5;
    const int h = bh & 15, b = bh >> 4;
    const int c = 16 + cm;
    const int p0 = (bh * 16 + cm) * 2;
    const int tid = threadIdx.x;

    if (tid < 64)
        ls[tid] = lpart[p0 * 64 + tid] + lpart[(p0 + 1) * 64 + tid];
    __syncthreads();

    const float* o0 = Opart + (size_t)p0 * 4096;
    const float* o1 = o0 + 4096;
    int d = tid >> 2, q0 = (tid & 3) * 16;
    #pragma unroll
    for (int j = 0; j < 4; ++j) {
        int off = d * 64 + q0 + j * 4;
        float4 a = *(const float4*)(o0 + off);
        float4 bv = *(const float4*)(o1 + off);
        Ot[d * 65 + q0 + j * 4 + 0] = (a.x + bv.x) / ls[q0 + j * 4 + 0];
        Ot[d * 65 + q0 + j * 4 + 1] = (a.y + bv.y) / ls[q0 + j * 4 + 1];
        Ot[d * 65 + q0 + j * 4 + 2] = (a.z + bv.z) / ls[q0 + j * 4 + 2];
        Ot[d * 65 + q0 + j * 4 + 3] = (a.w + bv.w) / ls[q0 + j * 4 + 3];
    }
    __syncthreads();
    int q = tid & 63, db = tid >> 6;
    alignas(16) short vals[16];
    #pragma unroll
    for (int j = 0; j < 16; ++j)
        vals[j] = f2bf(Ot[(db * 16 + j) * 65 + q]);
    short* ob = attn + (size_t)(b * S_ + c * 64 + q) * D_ + h * 64 + db * 16;
    *(uint4*)ob     = *(const uint4*)&vals[0];
    *(uint4*)(ob+8) = *(const uint4*)&vals[8];
}

extern "C" void kernel_launch(void* const* d_in, const int* in_sizes, int n_in,
                              void* d_out, int out_size, void* d_ws, size_t ws_size,
                              hipStream_t stream) {
    const float* x  = (const float*)d_in[0];
    const float* Wq = (const float*)d_in[1];
    const float* Wk = (const float*)d_in[2];
    const float* Wv = (const float*)d_in[3];
    const float* Wo = (const float*)d_in[4];
    const int* poff = (const int*)d_in[5];
    float* out = (float*)d_out;

    short* xb  = (short*)d_ws;                      // [4096][1024]
    short* wt  = xb  + (size_t)NTOK * D_;           // [1536][1024] fused Wqkv^T
    short* woT = wt  + (size_t)NQKV * D_;           // [1024][1024] Wo^T
    short* qkb = woT + (size_t)D_ * D_;             // [4096][1280]
    short* vbT = qkb + (size_t)NTOK * NQK;          // [256][4096]
    short* ab  = vbT + (size_t)(HKV_*DH_) * NTOK;   // [4096][1024]
    float* Opart = (float*)(ab + (size_t)NTOK * D_); // [1024][64][64] fp32
    float* lpart = Opart + (size_t)1024 * 4096;      // [1024][64] fp32

    prep_kernel<<<dim3(4096 + 1024 + 256 + 256 + 1024), 256, 0, stream>>>(
        x, Wq, Wk, Wv, Wo, xb, wt, woT);
    gemm_tn_kernel<2><<<dim3(NQKV / 128, NTOK / 64), 256, 0, stream>>>(
        xb, wt, qkb, nullptr, vbT, NQK);
    ropek_kernel<<<dim3(NTOK * 4 * 32 / 256), 256, 0, stream>>>(qkb, poff);
    attn_kernel7<<<dim3(1536), 256, 0, stream>>>(qkb, vbT, ab, Opart, lpart, poff);
    attn_merge_kernel<<<dim3(512), 256, 0, stream>>>(Opart, lpart, ab);
    gemm_tn_kernel<1><<<dim3(D_ / 128, NTOK / 64), 256, 0, stream>>>(
        ab, woT, nullptr, out, nullptr, D_);
}